// Round 14
// baseline (903.121 us; speedup 1.0000x reference)
//
#include <hip/hip_runtime.h>
#include <stdint.h>
#include <math.h>

#define NB 8
#define NDIM 384
#define NHD 8
#define DHD 48

// ---------------- persistent device buffers (f32) ----------------
__device__ float g_patch[2048 * 1536];
__device__ float g_x[NB * 256 * NDIM];
__device__ float g_xb[NB * 64 * NDIM];
__device__ float g_xq[NB * NHD * 256 * DHD];
__device__ float g_xk[NB * NHD * 256 * DHD];
__device__ float g_xv[NB * NHD * 256 * DHD];
__device__ float g_q4[NB * 256 * NDIM];
__device__ float g_k4[NB * 256 * NDIM];
__device__ float g_q[NB * 256 * NDIM];
__device__ float g_k[NB * 256 * NDIM];
__device__ float g_rm0[NB * 256 * NHD];
__device__ float g_rmd[NB * NHD * 256];
__device__ float g_score[NB * NHD * 256 * 256];   // also scratch for emb split-K partials
__device__ float g_score2[NB * NHD * 256 * 256];
__device__ float g_logits[NB * 256 * 64];
__device__ float g_tmp[NB * 64 * 256];
__device__ float g_e1[NB * 64 * 256];
__device__ float g_adj2[NB * 64 * 64];
__device__ float g_lg2[NB * 64];

__device__ __forceinline__ float* dev_buf(int s) {
  switch (s) {
    case 0: return g_patch;
    case 1: return g_x;
    case 2: return g_q4;
    case 3: return g_k4;
    case 4: return g_q;
    case 5: return g_k;
    case 6: return g_logits;
    default: return nullptr;
  }
}
#define SEL_PATCH 0
#define SEL_X 1
#define SEL_Q4 2
#define SEL_K4 3
#define SEL_Q 4
#define SEL_K 5
#define SEL_LOGITS 6

__device__ __forceinline__ float gelu_f(float x) {
  return 0.5f * x * (1.0f + erff(x * 0.70710678118654752440f));
}

// ---------------- JAX threefry2x32 (20 rounds) ----------------
__host__ __device__ inline void threefry2x32(uint32_t k0, uint32_t k1,
                                             uint32_t x0, uint32_t x1,
                                             uint32_t* o0, uint32_t* o1) {
  uint32_t ks2 = k0 ^ k1 ^ 0x1BD11BDAu;
#define TF_R(r) { x0 += x1; x1 = (x1 << (r)) | (x1 >> (32 - (r))); x1 ^= x0; }
  x0 += k0; x1 += k1;
  TF_R(13) TF_R(15) TF_R(26) TF_R(6)
  x0 += k1; x1 += ks2 + 1u;
  TF_R(17) TF_R(29) TF_R(16) TF_R(24)
  x0 += ks2; x1 += k0 + 2u;
  TF_R(13) TF_R(15) TF_R(26) TF_R(6)
  x0 += k0; x1 += k1 + 3u;
  TF_R(17) TF_R(29) TF_R(16) TF_R(24)
  x0 += k1; x1 += ks2 + 4u;
  TF_R(13) TF_R(15) TF_R(26) TF_R(6)
  x0 += ks2; x1 += k0 + 5u;
#undef TF_R
  *o0 = x0; *o1 = x1;
}

// modern JAX threefry_partitionable: counter (0, idx), bits = o0 ^ o1
__device__ __forceinline__ double gumbel_from(uint32_t k0, uint32_t k1,
                                              uint32_t idx) {
  uint32_t o0, o1;
  threefry2x32(k0, k1, 0u, idx, &o0, &o1);
  uint32_t bits = o0 ^ o1;
  uint32_t ub = (bits >> 9) | 0x3f800000u;
  float f = __uint_as_float(ub) - 1.0f;
  const float tiny = 1.17549435e-38f;
  float u = fmaxf(f + tiny, tiny);
  return -log(-log((double)u));
}

// ---------------- patch pipeline: block per (patch, 96-ch chunk) ----------------
// conv1 weights staged in LDS (stride-27, wave-uniform broadcast reads); dwconv on 192 thr.
__global__ __launch_bounds__(256) void k_patch(const float* __restrict__ img,
                                               const float* __restrict__ w1, const float* __restrict__ b1,
                                               const float* __restrict__ bng, const float* __restrict__ bnb,
                                               const float* __restrict__ w2, const float* __restrict__ b2) {
  __shared__ float s_in[3 * 256];
  __shared__ float s_c1[96 * 49];
  __shared__ float s_w1[96 * 27];
  const float BN_INV = (float)0.99999500003749968752;
  int p = blockIdx.x >> 2;
  int chunk = blockIdx.x & 3;
  int obase = chunk * 96;
  int b = p >> 8, g = p & 255, gi = g >> 4, gj = g & 15;
  int tid = threadIdx.x;
  for (int idx = tid; idx < 3 * 256; idx += 256) {
    int c = idx >> 8, r = idx & 255, py = r >> 4, px = r & 15;
    float v = 0.f;
    if (py >= 1 && py <= 14 && px >= 1 && px <= 14)
      v = img[(((size_t)b * 3 + c) * 224 + gi * 14 + py - 1) * 224 + gj * 14 + px - 1];
    s_in[idx] = v;
  }
  const float4* wsrc = (const float4*)(w1 + obase * 27);
  for (int i = tid; i < 96 * 27 / 4; i += 256) ((float4*)s_w1)[i] = wsrc[i];
  __syncthreads();
  int wave = tid >> 6, lane = tid & 63;
  int y = lane / 7, x = lane - y * 7;
  bool act = lane < 49;
  float in[27];
#pragma unroll
  for (int c = 0; c < 3; ++c)
#pragma unroll
    for (int ky = 0; ky < 3; ++ky)
#pragma unroll
      for (int kx = 0; kx < 3; ++kx)
        in[c * 9 + ky * 3 + kx] = act ? s_in[c * 256 + (2 * y + ky) * 16 + (2 * x + kx)] : 0.f;

  for (int ci = 0; ci < 24; ci += 4) {
    int cl0 = wave * 24 + ci;
    int o0 = obase + cl0;
    float a0 = b1[o0], a1 = b1[o0 + 1], a2 = b1[o0 + 2], a3 = b1[o0 + 3];
    const float* wA = s_w1 + cl0 * 27;
#pragma unroll
    for (int j = 0; j < 27; ++j) {
      float ij = in[j];
      a0 += ij * wA[j];
      a1 += ij * wA[27 + j];
      a2 += ij * wA[54 + j];
      a3 += ij * wA[81 + j];
    }
    a0 = a0 * BN_INV * bng[o0] + bnb[o0];
    a1 = a1 * BN_INV * bng[o0 + 1] + bnb[o0 + 1];
    a2 = a2 * BN_INV * bng[o0 + 2] + bnb[o0 + 2];
    a3 = a3 * BN_INV * bng[o0 + 3] + bnb[o0 + 3];
    if (act) {
      s_c1[cl0 * 49 + lane] = gelu_f(a0);
      s_c1[(cl0 + 1) * 49 + lane] = gelu_f(a1);
      s_c1[(cl0 + 2) * 49 + lane] = gelu_f(a2);
      s_c1[(cl0 + 3) * 49 + lane] = gelu_f(a3);
    }
  }
  __syncthreads();
  if (tid < 192) {
    int cl = tid >> 1, half = tid & 1, c = obase + cl;
    float wd[9];
#pragma unroll
    for (int j = 0; j < 9; ++j) wd[j] = w2[c * 9 + j];
    float bb2 = b2[c];
    const float* sc = &s_c1[cl * 49];
    float o2[2][4];
#pragma unroll
    for (int y2 = 0; y2 < 2; ++y2) {
      int yy = half * 2 + y2;
#pragma unroll
      for (int xx = 0; xx < 4; ++xx) {
        float a = bb2;
#pragma unroll
        for (int ky = 0; ky < 3; ++ky) {
          int iy = 2 * yy + ky - 1;
          if (iy < 0 || iy >= 7) continue;
#pragma unroll
          for (int kx = 0; kx < 3; ++kx) {
            int ix = 2 * xx + kx - 1;
            if (ix < 0 || ix >= 7) continue;
            a += sc[iy * 7 + ix] * wd[ky * 3 + kx];
          }
        }
        o2[y2][xx] = a;
      }
    }
    float2 r;
    r.x = fmaxf(fmaxf(o2[0][0], o2[0][1]), fmaxf(o2[1][0], o2[1][1]));
    r.y = fmaxf(fmaxf(o2[0][2], o2[0][3]), fmaxf(o2[1][2], o2[1][3]));
    *(float2*)&g_patch[(size_t)p * 1536 + c * 4 + half * 2] = r;
  }
}

// ---------------- generic GEMM (K mult of 384): C = act(A@W + bias) (+resid) ----------------
template <int RPB>
__global__ void k_gemm(const float* __restrict__ W, const float* __restrict__ bias,
                       int selA, int selC, int selR,
                       int M, int K, int N, int act) {
  extern __shared__ float sA[];   // RPB * 384
  const float* A = dev_buf(selA);
  float* C = dev_buf(selC);
  const float* R = (selR >= 0) ? dev_buf(selR) : nullptr;
  int tid = threadIdx.x;
  int bs = blockDim.x;
  int r0 = blockIdx.x * RPB;
  float acc[RPB];
#pragma unroll
  for (int r = 0; r < RPB; ++r) acc[r] = 0.0f;
  const float4 z4 = {0.f, 0.f, 0.f, 0.f};
  for (int k0 = 0; k0 < K; k0 += 384) {
    __syncthreads();
    for (int idx = tid; idx < RPB * 96; idx += bs) {
      int r = idx / 96, q = idx - r * 96;
      int m = r0 + r;
      ((float4*)sA)[idx] = (m < M) ? ((const float4*)(A + (size_t)m * K + k0))[q] : z4;
    }
    __syncthreads();
    const float* Wp = W + (size_t)k0 * N + tid;
    float w0 = Wp[0], w1 = Wp[N], w2 = Wp[2 * (size_t)N], w3 = Wp[3 * (size_t)N];
#pragma unroll 2
    for (int k = 0; k < 384; k += 4) {
      float n0 = 0.f, n1 = 0.f, n2 = 0.f, n3 = 0.f;
      if (k + 4 < 384) {
        const float* Wn = Wp + (size_t)(k + 4) * N;
        n0 = Wn[0]; n1 = Wn[N]; n2 = Wn[2 * (size_t)N]; n3 = Wn[3 * (size_t)N];
      }
#pragma unroll
      for (int r = 0; r < RPB; ++r) {
        float4 a = *(const float4*)&sA[r * 384 + k];
        acc[r] += a.x * w0 + a.y * w1 + a.z * w2 + a.w * w3;
      }
      w0 = n0; w1 = n1; w2 = n2; w3 = n3;
    }
  }
#pragma unroll
  for (int r = 0; r < RPB; ++r) {
    int m = r0 + r;
    if (m >= M) break;
    float v = acc[r];
    if (bias) v += bias[tid];
    if (act == 1) v = gelu_f(v);
    if (R) v += R[(size_t)m * N + tid];
    C[(size_t)m * N + tid] = v;
  }
}

// ---------------- emb GEMM split-K: partials into g_score ----------------
__global__ __launch_bounds__(384) void k_gemm_sk(const float* __restrict__ W, int M, int K, int N) {
  __shared__ float sA[8 * 384];
  int mb = M >> 3;                  // blocks per K-chunk
  int kc = blockIdx.x / mb;
  int rb = blockIdx.x - kc * mb;
  int r0 = rb << 3;
  int k0 = kc * 384;
  int tid = threadIdx.x;
  float acc[8];
#pragma unroll
  for (int r = 0; r < 8; ++r) acc[r] = 0.0f;
  for (int idx = tid; idx < 8 * 96; idx += 384) {
    int r = idx / 96, q = idx - r * 96;
    ((float4*)sA)[idx] = ((const float4*)(g_patch + (size_t)(r0 + r) * K + k0))[q];
  }
  __syncthreads();
  const float* Wp = W + (size_t)k0 * N + tid;
  float w0 = Wp[0], w1 = Wp[N], w2 = Wp[2 * (size_t)N], w3 = Wp[3 * (size_t)N];
#pragma unroll 2
  for (int k = 0; k < 384; k += 4) {
    float n0 = 0.f, n1 = 0.f, n2 = 0.f, n3 = 0.f;
    if (k + 4 < 384) {
      const float* Wn = Wp + (size_t)(k + 4) * N;
      n0 = Wn[0]; n1 = Wn[N]; n2 = Wn[2 * (size_t)N]; n3 = Wn[3 * (size_t)N];
    }
#pragma unroll
    for (int r = 0; r < 8; ++r) {
      float4 a = *(const float4*)&sA[r * 384 + k];
      acc[r] += a.x * w0 + a.y * w1 + a.z * w2 + a.w * w3;
    }
    w0 = n0; w1 = n1; w2 = n2; w3 = n3;
  }
#pragma unroll
  for (int r = 0; r < 8; ++r)
    g_score[((size_t)kc * M + r0 + r) * N + tid] = acc[r];
}

// reduce 4 partials + bias -> g_x
__global__ void k_gemm_skred(const float* __restrict__ bias, int M, int N) {
  int i = blockIdx.x * blockDim.x + threadIdx.x;
  int total = M * N;
  if (i >= total) return;
  size_t stride = (size_t)M * N;
  float v = g_score[i] + g_score[i + stride] + g_score[i + 2 * stride] + g_score[i + 3 * stride];
  g_x[i] = v + bias[i % N];
}

// ---------------- dual GEMM for Q and K projections (one dispatch) ----------------
template <int RPB>
__global__ void k_gemmqk(const float* __restrict__ Wq_, const float* __restrict__ Wk_, int M) {
  __shared__ float sA[RPB * 384];
  int half = gridDim.x >> 1;
  bool isK = blockIdx.x >= half;
  int bid = isK ? blockIdx.x - half : blockIdx.x;
  const float* A = isK ? g_k4 : g_q4;
  float* C = isK ? g_k : g_q;
  const float* W = isK ? Wk_ : Wq_;
  const int N = 384;
  int tid = threadIdx.x;
  int r0 = bid * RPB;
  float acc[RPB];
#pragma unroll
  for (int r = 0; r < RPB; ++r) acc[r] = 0.0f;
  for (int idx = tid; idx < RPB * 96; idx += N) {
    int r = idx / 96, q = idx - r * 96;
    ((float4*)sA)[idx] = ((const float4*)(A + (size_t)(r0 + r) * 384))[q];
  }
  __syncthreads();
  const float* Wp = W + tid;
  float w0 = Wp[0], w1 = Wp[N], w2 = Wp[2 * (size_t)N], w3 = Wp[3 * (size_t)N];
#pragma unroll 2
  for (int k = 0; k < 384; k += 4) {
    float n0 = 0.f, n1 = 0.f, n2 = 0.f, n3 = 0.f;
    if (k + 4 < 384) {
      const float* Wn = Wp + (size_t)(k + 4) * N;
      n0 = Wn[0]; n1 = Wn[N]; n2 = Wn[2 * (size_t)N]; n3 = Wn[3 * (size_t)N];
    }
#pragma unroll
    for (int r = 0; r < RPB; ++r) {
      float4 a = *(const float4*)&sA[r * 384 + k];
      acc[r] += a.x * w0 + a.y * w1 + a.z * w2 + a.w * w3;
    }
    w0 = n0; w1 = n1; w2 = n2; w3 = n3;
  }
#pragma unroll
  for (int r = 0; r < RPB; ++r)
    C[(size_t)(r0 + r) * N + tid] = acc[r];
}

// ---------------- fused LayerNorm + GCN weight projection ----------------
__global__ __launch_bounds__(384) void k_lngcn(const float* __restrict__ gg, const float* __restrict__ bb,
                                               const float* __restrict__ Wq, const float* __restrict__ Wk,
                                               const float* __restrict__ Wv, int t) {
  __shared__ float xn[NDIM];
  __shared__ float wred[6];
  int row = blockIdx.x;          // b*t + tt
  int b = row / t, tt = row - b * t;
  int tid = threadIdx.x;
  int wid = tid >> 6, lane = tid & 63;
  float v = g_x[(size_t)row * NDIM + tid];
  float s = v;
#pragma unroll
  for (int off = 32; off > 0; off >>= 1) s += __shfl_xor(s, off);
  if (lane == 0) wred[wid] = s;
  __syncthreads();
  float tot = wred[0] + wred[1] + wred[2] + wred[3] + wred[4] + wred[5];
  float mean = tot * (1.0f / 384.0f);
  __syncthreads();
  float d = v - mean;
  s = d * d;
#pragma unroll
  for (int off = 32; off > 0; off >>= 1) s += __shfl_xor(s, off);
  if (lane == 0) wred[wid] = s;
  __syncthreads();
  tot = wred[0] + wred[1] + wred[2] + wred[3] + wred[4] + wred[5];
  float var = tot * (1.0f / 384.0f);
  float inv = 1.0f / sqrtf(var + 1e-5f);
  xn[tid] = d * inv * gg[tid] + bb[tid];
  __syncthreads();
  int h = tid / DHD, dd = tid - h * DHD;
  const float* xh = &xn[h * DHD];
  float aq = 0.f, ak = 0.f, av = 0.f;
#pragma unroll 4
  for (int e = 0; e < DHD; ++e) {
    float xv_ = xh[e];
    aq += xv_ * Wq[e * DHD + dd];
    ak += xv_ * Wk[e * DHD + dd];
    av += xv_ * Wv[e * DHD + dd];
  }
  size_t o = ((size_t)(b * NHD + h) * t + tt) * DHD + dd;
  g_xq[o] = aq; g_xk[o] = ak; g_xv[o] = av;
}

// ---------------- q4r/k4r = adj @ xq / adj @ xk — 8 rows per block ----------------
__global__ __launch_bounds__(64) void k_adjmm(const int* __restrict__ adji, int use_adj2, int t) {
  __shared__ float arow[8][256];
  int bid = blockIdx.x;
  int nt = t >> 3;
  int lt = bid % nt; int h = (bid / nt) % NHD; int b = bid / (nt * NHD);
  int l0 = lt * 8;
  int tid = threadIdx.x;
  for (int idx = tid; idx < 8 * t; idx += 64) {
    int r = idx / t, s2 = idx - r * t;
    arow[r][s2] = use_adj2 ? g_adj2[((size_t)b * t + l0 + r) * t + s2]
                           : (float)adji[(l0 + r) * 256 + s2];
  }
  __syncthreads();
  if (tid < DHD) {
    const float* xq = g_xq + (size_t)((b * NHD + h) * t) * DHD + tid;
    const float* xk = g_xk + (size_t)((b * NHD + h) * t) * DHD + tid;
    float aq[8] = {0.f, 0.f, 0.f, 0.f, 0.f, 0.f, 0.f, 0.f};
    float ak[8] = {0.f, 0.f, 0.f, 0.f, 0.f, 0.f, 0.f, 0.f};
    for (int s2 = 0; s2 < t; ++s2) {
      float xqv = xq[(size_t)s2 * DHD];
      float xkv = xk[(size_t)s2 * DHD];
#pragma unroll
      for (int r = 0; r < 8; ++r) {
        aq[r] += arow[r][s2] * xqv;
        ak[r] += arow[r][s2] * xkv;
      }
    }
#pragma unroll
    for (int r = 0; r < 8; ++r) {
      size_t o = ((size_t)b * t + l0 + r) * NDIM + h * DHD + tid;
      g_q4[o] = aq[r]; g_k4[o] = ak[r];
    }
  }
}

// ---------------- rm0 = gelu([q,k] @ w_kf)  (b*t, 8) ----------------
__global__ __launch_bounds__(64) void k_kf(const float* __restrict__ Wkf) {
  int row = blockIdx.x;
  int tid = threadIdx.x;
  const float* qrow = g_q + (size_t)row * NDIM;
  const float* krow = g_k + (size_t)row * NDIM;
  float accs[8];
#pragma unroll
  for (int j = 0; j < 8; ++j) accs[j] = 0.f;
  for (int m = tid; m < 768; m += 64) {
    float v = (m < 384) ? qrow[m] : krow[m - 384];
    const float* wr = Wkf + (size_t)m * 8;
#pragma unroll
    for (int j = 0; j < 8; ++j) accs[j] += v * wr[j];
  }
#pragma unroll
  for (int j = 0; j < 8; ++j) {
    float a = accs[j];
    for (int off = 32; off > 0; off >>= 1) a += __shfl_xor(a, off);
    if (tid == 0) g_rm0[(size_t)row * 8 + j] = gelu_f(a);
  }
}

// ---------------- fused rm + rmd ----------------
__global__ __launch_bounds__(256) void k_rmrmd(const float* __restrict__ Wp,
                                               const float* __restrict__ sDp, int t) {
  __shared__ float red[256];
  __shared__ float rm_s[64];
  int b = blockIdx.x; int tid = threadIdx.x;
  int out = tid & 63, slice = tid >> 6;
  int h = out >> 3, g = out & 7;
  int t4 = t >> 2;
  const float* base = g_rm0 + (size_t)b * t * 8 + (size_t)slice * t4 * 8;
  float acc = 0.f;
  for (int tt = 0; tt < t4; ++tt) acc += base[tt * 8 + h] * base[tt * 8 + g];
  red[slice * 64 + out] = acc;
  __syncthreads();
  if (tid < 64)
    rm_s[tid] = red[tid] + red[64 + tid] + red[128 + tid] + red[192 + tid];
  __syncthreads();
  for (int idx = tid; idx < NHD * t; idx += 256) {
    int s = idx % t; int hh = idx / t;
    const float* rm = rm_s + hh * 8;
    float a = 0.f;
#pragma unroll
    for (int gg = 0; gg < 8; ++gg) a += rm[gg] * Wp[gg * t + s];
    float val = a / sDp[hh * t + s];
    g_rmd[((size_t)(b * NHD + hh)) * t + s] = 1.0f / (1.0f + expf(-val));
  }
}

// ---------------- score: 8 q-rows per block; K row in registers ----------------
__global__ void k_score(float scale, int t) {
  __shared__ float qs[8][DHD];
  __shared__ float rl[8];
  int bid = blockIdx.x;
  int nt = t >> 3;
  int lt = bid % nt; int h = (bid / nt) % NHD; int b = bid / (nt * NHD);
  int l0 = lt * 8;
  int tid = threadIdx.x;
  for (int idx = tid; idx < 8 * DHD; idx += t) {
    int r = idx / DHD, d = idx - r * DHD;
    qs[r][d] = g_q[((size_t)b * t + l0 + r) * NDIM + h * DHD + d];
  }
  if (tid < 8) rl[tid] = g_rmd[(size_t)(b * NHD + h) * t + l0 + tid];
  __syncthreads();
  const float* krow = g_k + ((size_t)b * t + tid) * NDIM + h * DHD;
  float4 kr[12];
#pragma unroll
  for (int j = 0; j < 12; ++j) kr[j] = *(const float4*)&krow[j * 4];
  float rmd_s = g_rmd[(size_t)(b * NHD + h) * t + tid];
#pragma unroll
  for (int r = 0; r < 8; ++r) {
    float acc = 0.f;
#pragma unroll
    for (int j = 0; j < 12; ++j) {
      float4 qq = *(const float4*)&qs[r][j * 4];
      acc += kr[j].x * qq.x + kr[j].y * qq.y + kr[j].z * qq.z + kr[j].w * qq.w;
    }
    float v = acc * scale;
    v = (v >= 0.f) ? v : 0.01f * v;
    v = rl[r] * v * rmd_s;
    g_score[((size_t)(b * NHD + h) * t + l0 + r) * t + tid] = v;
  }
}

// ---------------- all-heads mix + mask + softmax per (b,l) ----------------
template <int T>
__global__ void k_mix8(const float* __restrict__ RM, const int* __restrict__ adji,
                       int use_adj2) {
  __shared__ float p[8][T];
  __shared__ float rmat[64];
  int bid = blockIdx.x;
  int l = bid % T, b = bid / T;
  int tt = threadIdx.x;
  if (tt < 64) rmat[tt] = RM[tt];
  __syncthreads();
  float sv[8];
#pragma unroll
  for (int h = 0; h < 8; ++h)
    sv[h] = g_score[((size_t)(b * NHD + h) * T + l) * T + tt];
  bool m = use_adj2 ? (g_adj2[((size_t)b * T + l) * T + tt] > 0.f)
                    : (adji[l * 256 + tt] > 0);
#pragma unroll
  for (int g = 0; g < 8; ++g) {
    float a = 0.f;
#pragma unroll
    for (int h = 0; h < 8; ++h) a += rmat[g * 8 + h] * sv[h];
    p[g][tt] = m ? a : -1e12f;
  }
  __syncthreads();
  int wid = tt >> 6, lane = tt & 63;
  const int NW = T / 64;
  const int RPW = 8 / NW;
  const int EPL = T / 64;
  for (int rr = 0; rr < RPW; ++rr) {
    int row = wid * RPW + rr;
    float mv = -1e30f;
#pragma unroll
    for (int e = 0; e < EPL; ++e) mv = fmaxf(mv, p[row][lane + e * 64]);
#pragma unroll
    for (int off = 32; off > 0; off >>= 1) mv = fmaxf(mv, __shfl_xor(mv, off));
    float sum = 0.f;
#pragma unroll
    for (int e = 0; e < EPL; ++e) {
      float ev = expf(p[row][lane + e * 64] - mv);
      p[row][lane + e * 64] = ev;
      sum += ev;
    }
#pragma unroll
    for (int off = 32; off > 0; off >>= 1) sum += __shfl_xor(sum, off);
    float inv = 1.0f / sum;
#pragma unroll
    for (int e = 0; e < EPL; ++e) p[row][lane + e * 64] *= inv;
  }
  __syncthreads();
#pragma unroll
  for (int h = 0; h < 8; ++h)
    g_score2[((size_t)(b * NHD + h) * T + l) * T + tt] = p[h][tt];
}

// ---------------- v4r = attn @ xv — 8 rows per block ----------------
__global__ __launch_bounds__(64) void k_attnv(int t) {
  __shared__ float arow[8][256];
  int bid = blockIdx.x;
  int nt = t >> 3;
  int lt = bid % nt; int h = (bid / nt) % NHD; int b = bid / (nt * NHD);
  int l0 = lt * 8;
  int tid = threadIdx.x;
  for (int idx = tid; idx < 8 * t; idx += 64) {
    int r = idx / t, s2 = idx - r * t;
    arow[r][s2] = g_score2[((size_t)(b * NHD + h) * t + l0 + r) * t + s2];
  }
  __syncthreads();
  if (tid < DHD) {
    const float* xv = g_xv + (size_t)((b * NHD + h) * t) * DHD + tid;
    float acc[8] = {0.f, 0.f, 0.f, 0.f, 0.f, 0.f, 0.f, 0.f};
    for (int s2 = 0; s2 < t; ++s2) {
      float xvv = xv[(size_t)s2 * DHD];
#pragma unroll
      for (int r = 0; r < 8; ++r) acc[r] += arow[r][s2] * xvv;
    }
#pragma unroll
    for (int r = 0; r < 8; ++r)
      g_q4[((size_t)b * t + l0 + r) * NDIM + h * DHD + tid] = acc[r];
  }
}

// ---------------- gumbel softmax for pooling: tmp[b,j,:] over 256 ----------------
__global__ __launch_bounds__(256) void k_gumbel_pool(uint32_t k0, uint32_t k1) {
  __shared__ double red2[256];
  int bj = blockIdx.x;   // b*64 + j
  int b = bj >> 6, j = bj & 63;
  int tt = threadIdx.x;
  uint32_t n = (uint32_t)bj * 256u + (uint32_t)tt;
  double gum = gumbel_from(k0, k1, n);
  double val = (double)g_logits[((size_t)b * 256 + tt) * 64 + j] + gum;
  red2[tt] = val; __syncthreads();
  for (int s = 128; s > 0; s >>= 1) { if (tt < s) red2[tt] = fmax(red2[tt], red2[tt + s]); __syncthreads(); }
  double mx = red2[0]; __syncthreads();
  double e = exp(val - mx);
  red2[tt] = e; __syncthreads();
  for (int s = 128; s > 0; s >>= 1) { if (tt < s) red2[tt] += red2[tt + s]; __syncthreads(); }
  g_tmp[(size_t)bj * 256 + tt] = (float)(e / red2[0]);
}

// ---------------- xb[b,j,:] = tmp[b,j,:] @ x[b,:,:] ----------------
__global__ __launch_bounds__(384) void k_poolx() {
  __shared__ float trow[256];
  int bj = blockIdx.x; int b = bj >> 6;
  int tid = threadIdx.x;
  if (tid < 256) trow[tid] = g_tmp[(size_t)bj * 256 + tid];
  __syncthreads();
  float acc = 0.f;
  const float* xb = g_x + (size_t)b * 256 * NDIM + tid;
  for (int tt = 0; tt < 256; ++tt) acc += trow[tt] * xb[(size_t)tt * NDIM];
  g_xb[(size_t)bj * NDIM + tid] = acc;
}

__global__ void k_copyx(int n) {
  int i = blockIdx.x * blockDim.x + threadIdx.x;
  if (i < n) g_x[i] = g_xb[i];
}

// ---------------- e1[b,l,t] = sum_s tmp[b,l,s]*adj[s,t] ----------------
__global__ __launch_bounds__(256) void k_pooladj1(const int* __restrict__ adji) {
  __shared__ float trow[256];
  int bl = blockIdx.x;
  int tid = threadIdx.x;
  trow[tid] = g_tmp[(size_t)bl * 256 + tid];
  __syncthreads();
  float acc = 0.f;
  for (int s = 0; s < 256; ++s) acc += trow[s] * (float)adji[s * 256 + tid];
  g_e1[(size_t)bl * 256 + tid] = acc;
}

// ---------------- adj2[b,l,m] = sum_t e1[b,l,t]*tmp[b,m,t] ----------------
__global__ __launch_bounds__(64) void k_pooladj2() {
  __shared__ float erow[256];
  int bl = blockIdx.x; int b = bl >> 6;
  int tid = threadIdx.x;
  for (int s = tid; s < 256; s += 64) erow[s] = g_e1[(size_t)bl * 256 + s];
  __syncthreads();
  const float* tm = g_tmp + ((size_t)b * 64 + tid) * 256;
  float acc = 0.f;
  for (int s = 0; s < 256; ++s) acc += erow[s] * tm[s];
  g_adj2[(size_t)bl * 64 + tid] = acc;
}

// ---------------- final logits: x @ upoolout_w + b ----------------
__global__ __launch_bounds__(64) void k_outlogits(const float* __restrict__ w, const float* __restrict__ bias) {
  int row = blockIdx.x;
  int tid = threadIdx.x;
  const float* x = g_x + (size_t)row * NDIM;
  float acc = 0.f;
  for (int c = tid; c < NDIM; c += 64) acc += x[c] * w[c];
  for (int off = 32; off > 0; off >>= 1) acc += __shfl_xor(acc, off);
  if (tid == 0) g_lg2[row] = acc + bias[0];
}

// ---------------- final gumbel softmax + weighted sum -> out ----------------
__global__ __launch_bounds__(384) void k_final(uint32_t k0, uint32_t k1, float* __restrict__ out) {
  __shared__ double sv[64];
  __shared__ double sp[64];
  int b = blockIdx.x;
  int tid = threadIdx.x;
  if (tid < 64) {
    uint32_t n = (uint32_t)(b * 64 + tid);
    sv[tid] = (double)g_lg2[b * 64 + tid] + gumbel_from(k0, k1, n);
  }
  __syncthreads();
  double mx = -1e30;
  for (int i2 = 0; i2 < 64; ++i2) mx = fmax(mx, sv[i2]);
  if (tid < 64) sp[tid] = exp(sv[tid] - mx);
  __syncthreads();
  double sum = 0.;
  for (int i2 = 0; i2 < 64; ++i2) sum += sp[i2];
  float acc = 0.f;
  const float* xb = g_x + (size_t)b * 64 * NDIM + tid;
  for (int tt = 0; tt < 64; ++tt) acc += (float)(sp[tt] / sum) * xb[(size_t)tt * NDIM];
  out[(size_t)b * NDIM + tid] = acc;
}

// ---------------- host ----------------
extern "C" void kernel_launch(void* const* d_in, const int* in_sizes, int n_in,
                              void* d_out, int out_size, void* d_ws, size_t ws_size,
                              hipStream_t stream) {
  const float* img = (const float*)d_in[0];
  const int* adj = (const int*)d_in[1];
  const float* ln_g = (const float*)d_in[2];
  const float* ln_b = (const float*)d_in[3];
  const float* gcn_wq = (const float*)d_in[4];
  const float* gcn_wk = (const float*)d_in[5];
  const float* gcn_wv = (const float*)d_in[6];
  const float* wq = (const float*)d_in[7];
  const float* wk = (const float*)d_in[8];
  const float* wv = (const float*)d_in[9];
  const float* w_kf = (const float*)d_in[10];
  const float* w_kf2 = (const float*)d_in[11];
  const float* w_kf3 = (const float*)d_in[12];
  const float* sD = (const float*)d_in[13];
  const float* sD2 = (const float*)d_in[14];
  const float* randmat = (const float*)d_in[15];
  const float* conv1_w = (const float*)d_in[16];
  const float* conv1_b = (const float*)d_in[17];
  const float* bn_g = (const float*)d_in[18];
  const float* bn_b = (const float*)d_in[19];
  const float* conv2_w = (const float*)d_in[20];
  const float* conv2_b = (const float*)d_in[21];
  const float* emb_w = (const float*)d_in[22];
  const float* emb_b = (const float*)d_in[23];
  const float* upool_w = (const float*)d_in[24];
  const float* upool_b = (const float*)d_in[25];
  const float* upoolout_w = (const float*)d_in[26];
  const float* upoolout_b = (const float*)d_in[27];
  float* out = (float*)d_out;

  uint32_t k2a, k2b, k99a, k99b;
  threefry2x32(0u, 42u, 0u, 2u, &k2a, &k2b);
  threefry2x32(0u, 42u, 0u, 99u, &k99a, &k99b);

  const float SCALE = (float)(1.0 / sqrt(384.0));

  k_patch<<<2048 * 4, 256, 0, stream>>>(img, conv1_w, conv1_b, bn_g, bn_b, conv2_w, conv2_b);
  k_gemm_sk<<<1024, 384, 0, stream>>>(emb_w, 2048, 1536, 384);
  k_gemm_skred<<<(2048 * 384 + 255) / 256, 256, 0, stream>>>(emb_b, 2048, 384);

  auto attention = [&](int i, int t, int label) {
    int rows = NB * t;
    int bht8 = NB * NHD * t / 8;
    int use_adj2 = (t == 64) ? 1 : 0;
    k_lngcn<<<rows, 384, 0, stream>>>(ln_g + i * 384, ln_b + i * 384,
                                      gcn_wq + i * 2304, gcn_wk + i * 2304,
                                      gcn_wv + i * 2304, t);
    k_adjmm<<<bht8, 64, 0, stream>>>(adj, use_adj2, t);
    if (rows == 2048) {
      k_gemmqk<4><<<1024, 384, 0, stream>>>(wq + i * 147456, wk + i * 147456, rows);
    } else {
      k_gemmqk<2><<<512, 384, 0, stream>>>(wq + i * 147456, wk + i * 147456, rows);
    }
    k_kf<<<rows, 64, 0, stream>>>(w_kf + i * 6144);
    const float* Wp = label ? (w_kf3 + i * 512) : (w_kf2 + i * 2048);
    const float* sDp = label ? (sD2 + i * 512) : (sD + i * 2048);
    k_rmrmd<<<NB, 256, 0, stream>>>(Wp, sDp, t);
    k_score<<<bht8, t, 0, stream>>>(SCALE, t);
    if (t == 256) {
      k_mix8<256><<<rows, 256, 0, stream>>>(randmat + i * 64, adj, use_adj2);
    } else {
      k_mix8<64><<<rows, 64, 0, stream>>>(randmat + i * 64, adj, use_adj2);
    }
    k_attnv<<<bht8, 64, 0, stream>>>(t);
    if (rows == 2048) {
      k_gemm<4><<<512, 384, 4 * 384 * sizeof(float), stream>>>(
          wv + i * 147456, nullptr, SEL_Q4, SEL_X, SEL_X, rows, 384, 384, 1);
    } else {
      k_gemm<2><<<256, 384, 2 * 384 * sizeof(float), stream>>>(
          wv + i * 147456, nullptr, SEL_Q4, SEL_X, SEL_X, rows, 384, 384, 1);
    }
  };

  attention(0, 256, 0);
  attention(1, 256, 0);

  // pooling at i==2
  k_gemm<2><<<1024, 64, 2 * 384 * sizeof(float), stream>>>(
      upool_w, upool_b, SEL_X, SEL_LOGITS, -1, 2048, 384, 64, 0);
  k_gumbel_pool<<<512, 256, 0, stream>>>(k2a, k2b);
  k_poolx<<<512, 384, 0, stream>>>();
  k_copyx<<<(NB * 64 * NDIM + 255) / 256, 256, 0, stream>>>(NB * 64 * NDIM);
  k_pooladj1<<<512, 256, 0, stream>>>(adj);
  k_pooladj2<<<512, 64, 0, stream>>>();

  attention(2, 64, 1);
  attention(3, 64, 1);

  k_outlogits<<<512, 64, 0, stream>>>(upoolout_w, upoolout_b);
  k_final<<<8, 384, 0, stream>>>(k99a, k99b, out);
}

// Round 15
// 895.597 us; speedup vs baseline: 1.0084x; 1.0084x over previous
//
#include <hip/hip_runtime.h>
#include <stdint.h>
#include <math.h>

#define NB 8
#define NDIM 384
#define NHD 8
#define DHD 48

// ---------------- persistent device buffers (f32) ----------------
__device__ float g_patch[2048 * 1536];
__device__ float g_x[NB * 256 * NDIM];
__device__ float g_xb[NB * 64 * NDIM];
__device__ float g_xq[NB * NHD * 256 * DHD];
__device__ float g_xk[NB * NHD * 256 * DHD];
__device__ float g_xv[NB * NHD * 256 * DHD];
__device__ float g_q4[NB * 256 * NDIM];
__device__ float g_k4[NB * 256 * NDIM];
__device__ float g_q[NB * 256 * NDIM];
__device__ float g_k[NB * 256 * NDIM];
__device__ float g_rm0[NB * 256 * NHD];
__device__ float g_rmd[NB * NHD * 256];
__device__ float g_score[NB * NHD * 256 * 256];   // also scratch for emb split-K partials
__device__ float g_score2[NB * NHD * 256 * 256];
__device__ float g_logits[NB * 256 * 64];
__device__ float g_tmp[NB * 64 * 256];
__device__ float g_e1[NB * 64 * 256];
__device__ float g_adj2[NB * 64 * 64];
__device__ float g_lg2[NB * 64];

__device__ __forceinline__ float* dev_buf(int s) {
  switch (s) {
    case 0: return g_patch;
    case 1: return g_x;
    case 2: return g_q4;
    case 3: return g_k4;
    case 4: return g_q;
    case 5: return g_k;
    case 6: return g_logits;
    default: return nullptr;
  }
}
#define SEL_PATCH 0
#define SEL_X 1
#define SEL_Q4 2
#define SEL_K4 3
#define SEL_Q 4
#define SEL_K 5
#define SEL_LOGITS 6

__device__ __forceinline__ float gelu_f(float x) {
  return 0.5f * x * (1.0f + erff(x * 0.70710678118654752440f));
}

// ---------------- JAX threefry2x32 (20 rounds) ----------------
__host__ __device__ inline void threefry2x32(uint32_t k0, uint32_t k1,
                                             uint32_t x0, uint32_t x1,
                                             uint32_t* o0, uint32_t* o1) {
  uint32_t ks2 = k0 ^ k1 ^ 0x1BD11BDAu;
#define TF_R(r) { x0 += x1; x1 = (x1 << (r)) | (x1 >> (32 - (r))); x1 ^= x0; }
  x0 += k0; x1 += k1;
  TF_R(13) TF_R(15) TF_R(26) TF_R(6)
  x0 += k1; x1 += ks2 + 1u;
  TF_R(17) TF_R(29) TF_R(16) TF_R(24)
  x0 += ks2; x1 += k0 + 2u;
  TF_R(13) TF_R(15) TF_R(26) TF_R(6)
  x0 += k0; x1 += k1 + 3u;
  TF_R(17) TF_R(29) TF_R(16) TF_R(24)
  x0 += k1; x1 += ks2 + 4u;
  TF_R(13) TF_R(15) TF_R(26) TF_R(6)
  x0 += ks2; x1 += k0 + 5u;
#undef TF_R
  *o0 = x0; *o1 = x1;
}

// modern JAX threefry_partitionable: counter (0, idx), bits = o0 ^ o1
__device__ __forceinline__ double gumbel_from(uint32_t k0, uint32_t k1,
                                              uint32_t idx) {
  uint32_t o0, o1;
  threefry2x32(k0, k1, 0u, idx, &o0, &o1);
  uint32_t bits = o0 ^ o1;
  uint32_t ub = (bits >> 9) | 0x3f800000u;
  float f = __uint_as_float(ub) - 1.0f;
  const float tiny = 1.17549435e-38f;
  float u = fmaxf(f + tiny, tiny);
  return -log(-log((double)u));
}

// ---------------- patch pipeline: block per (patch, 96-ch chunk) ----------------
// conv1 weights staged TRANSPOSED (j-major) in LDS -> one float4 broadcast per j
// covers 4 unrolled channels; dwconv tail on 96 threads (round-12 form).
__global__ __launch_bounds__(256) void k_patch(const float* __restrict__ img,
                                               const float* __restrict__ w1, const float* __restrict__ b1,
                                               const float* __restrict__ bng, const float* __restrict__ bnb,
                                               const float* __restrict__ w2, const float* __restrict__ b2) {
  __shared__ float s_in[3 * 256];
  __shared__ float s_c1[96 * 49];
  __shared__ __align__(16) float s_w1t[27 * 96];   // [j][ch]
  const float BN_INV = (float)0.99999500003749968752;
  int p = blockIdx.x >> 2;
  int chunk = blockIdx.x & 3;
  int obase = chunk * 96;
  int b = p >> 8, g = p & 255, gi = g >> 4, gj = g & 15;
  int tid = threadIdx.x;
  for (int idx = tid; idx < 3 * 256; idx += 256) {
    int c = idx >> 8, r = idx & 255, py = r >> 4, px = r & 15;
    float v = 0.f;
    if (py >= 1 && py <= 14 && px >= 1 && px <= 14)
      v = img[(((size_t)b * 3 + c) * 224 + gi * 14 + py - 1) * 224 + gj * 14 + px - 1];
    s_in[idx] = v;
  }
  for (int i = tid; i < 96 * 27; i += 256) {
    int ch = i / 27, j = i - ch * 27;
    s_w1t[j * 96 + ch] = w1[(size_t)obase * 27 + i];
  }
  __syncthreads();
  int wave = tid >> 6, lane = tid & 63;
  int y = lane / 7, x = lane - y * 7;
  bool act = lane < 49;
  float in[27];
#pragma unroll
  for (int c = 0; c < 3; ++c)
#pragma unroll
    for (int ky = 0; ky < 3; ++ky)
#pragma unroll
      for (int kx = 0; kx < 3; ++kx)
        in[c * 9 + ky * 3 + kx] = act ? s_in[c * 256 + (2 * y + ky) * 16 + (2 * x + kx)] : 0.f;

  for (int ci = 0; ci < 24; ci += 4) {
    int cl0 = wave * 24 + ci;          // multiple of 4 -> float4-aligned
    int o0 = obase + cl0;
    float a0 = b1[o0], a1 = b1[o0 + 1], a2 = b1[o0 + 2], a3 = b1[o0 + 3];
#pragma unroll
    for (int j = 0; j < 27; ++j) {
      float4 w = *(const float4*)&s_w1t[j * 96 + cl0];
      float ij = in[j];
      a0 += ij * w.x;
      a1 += ij * w.y;
      a2 += ij * w.z;
      a3 += ij * w.w;
    }
    a0 = a0 * BN_INV * bng[o0] + bnb[o0];
    a1 = a1 * BN_INV * bng[o0 + 1] + bnb[o0 + 1];
    a2 = a2 * BN_INV * bng[o0 + 2] + bnb[o0 + 2];
    a3 = a3 * BN_INV * bng[o0 + 3] + bnb[o0 + 3];
    if (act) {
      s_c1[cl0 * 49 + lane] = gelu_f(a0);
      s_c1[(cl0 + 1) * 49 + lane] = gelu_f(a1);
      s_c1[(cl0 + 2) * 49 + lane] = gelu_f(a2);
      s_c1[(cl0 + 3) * 49 + lane] = gelu_f(a3);
    }
  }
  __syncthreads();
  if (tid < 96) {
    int cl = tid, c = obase + cl;
    float wd[9];
#pragma unroll
    for (int j = 0; j < 9; ++j) wd[j] = w2[c * 9 + j];
    float bb2 = b2[c];
    const float* sc = &s_c1[cl * 49];
    float o2[4][4];
#pragma unroll
    for (int yy = 0; yy < 4; ++yy)
#pragma unroll
      for (int xx = 0; xx < 4; ++xx) {
        float a = bb2;
#pragma unroll
        for (int ky = 0; ky < 3; ++ky) {
          int iy = 2 * yy + ky - 1;
          if (iy < 0 || iy >= 7) continue;
#pragma unroll
          for (int kx = 0; kx < 3; ++kx) {
            int ix = 2 * xx + kx - 1;
            if (ix < 0 || ix >= 7) continue;
            a += sc[iy * 7 + ix] * wd[ky * 3 + kx];
          }
        }
        o2[yy][xx] = a;
      }
    float4 r;
    r.x = fmaxf(fmaxf(o2[0][0], o2[0][1]), fmaxf(o2[1][0], o2[1][1]));
    r.y = fmaxf(fmaxf(o2[0][2], o2[0][3]), fmaxf(o2[1][2], o2[1][3]));
    r.z = fmaxf(fmaxf(o2[2][0], o2[2][1]), fmaxf(o2[3][0], o2[3][1]));
    r.w = fmaxf(fmaxf(o2[2][2], o2[2][3]), fmaxf(o2[3][2], o2[3][3]));
    *(float4*)&g_patch[(size_t)p * 1536 + c * 4] = r;
  }
}

// ---------------- generic GEMM (K mult of 384): C = act(A@W + bias) (+resid) ----------------
template <int RPB>
__global__ void k_gemm(const float* __restrict__ W, const float* __restrict__ bias,
                       int selA, int selC, int selR,
                       int M, int K, int N, int act) {
  extern __shared__ float sA[];   // RPB * 384
  const float* A = dev_buf(selA);
  float* C = dev_buf(selC);
  const float* R = (selR >= 0) ? dev_buf(selR) : nullptr;
  int tid = threadIdx.x;
  int bs = blockDim.x;
  int r0 = blockIdx.x * RPB;
  float acc[RPB];
#pragma unroll
  for (int r = 0; r < RPB; ++r) acc[r] = 0.0f;
  const float4 z4 = {0.f, 0.f, 0.f, 0.f};
  for (int k0 = 0; k0 < K; k0 += 384) {
    __syncthreads();
    for (int idx = tid; idx < RPB * 96; idx += bs) {
      int r = idx / 96, q = idx - r * 96;
      int m = r0 + r;
      ((float4*)sA)[idx] = (m < M) ? ((const float4*)(A + (size_t)m * K + k0))[q] : z4;
    }
    __syncthreads();
    const float* Wp = W + (size_t)k0 * N + tid;
    float w0 = Wp[0], w1 = Wp[N], w2 = Wp[2 * (size_t)N], w3 = Wp[3 * (size_t)N];
#pragma unroll 2
    for (int k = 0; k < 384; k += 4) {
      float n0 = 0.f, n1 = 0.f, n2 = 0.f, n3 = 0.f;
      if (k + 4 < 384) {
        const float* Wn = Wp + (size_t)(k + 4) * N;
        n0 = Wn[0]; n1 = Wn[N]; n2 = Wn[2 * (size_t)N]; n3 = Wn[3 * (size_t)N];
      }
#pragma unroll
      for (int r = 0; r < RPB; ++r) {
        float4 a = *(const float4*)&sA[r * 384 + k];
        acc[r] += a.x * w0 + a.y * w1 + a.z * w2 + a.w * w3;
      }
      w0 = n0; w1 = n1; w2 = n2; w3 = n3;
    }
  }
#pragma unroll
  for (int r = 0; r < RPB; ++r) {
    int m = r0 + r;
    if (m >= M) break;
    float v = acc[r];
    if (bias) v += bias[tid];
    if (act == 1) v = gelu_f(v);
    if (R) v += R[(size_t)m * N + tid];
    C[(size_t)m * N + tid] = v;
  }
}

// ---------------- emb GEMM split-K: partials into g_score ----------------
__global__ __launch_bounds__(384) void k_gemm_sk(const float* __restrict__ W, int M, int K, int N) {
  __shared__ float sA[8 * 384];
  int mb = M >> 3;                  // blocks per K-chunk
  int kc = blockIdx.x / mb;
  int rb = blockIdx.x - kc * mb;
  int r0 = rb << 3;
  int k0 = kc * 384;
  int tid = threadIdx.x;
  float acc[8];
#pragma unroll
  for (int r = 0; r < 8; ++r) acc[r] = 0.0f;
  for (int idx = tid; idx < 8 * 96; idx += 384) {
    int r = idx / 96, q = idx - r * 96;
    ((float4*)sA)[idx] = ((const float4*)(g_patch + (size_t)(r0 + r) * K + k0))[q];
  }
  __syncthreads();
  const float* Wp = W + (size_t)k0 * N + tid;
  float w0 = Wp[0], w1 = Wp[N], w2 = Wp[2 * (size_t)N], w3 = Wp[3 * (size_t)N];
#pragma unroll 2
  for (int k = 0; k < 384; k += 4) {
    float n0 = 0.f, n1 = 0.f, n2 = 0.f, n3 = 0.f;
    if (k + 4 < 384) {
      const float* Wn = Wp + (size_t)(k + 4) * N;
      n0 = Wn[0]; n1 = Wn[N]; n2 = Wn[2 * (size_t)N]; n3 = Wn[3 * (size_t)N];
    }
#pragma unroll
    for (int r = 0; r < 8; ++r) {
      float4 a = *(const float4*)&sA[r * 384 + k];
      acc[r] += a.x * w0 + a.y * w1 + a.z * w2 + a.w * w3;
    }
    w0 = n0; w1 = n1; w2 = n2; w3 = n3;
  }
#pragma unroll
  for (int r = 0; r < 8; ++r)
    g_score[((size_t)kc * M + r0 + r) * N + tid] = acc[r];
}

// reduce 4 partials + bias -> g_x
__global__ void k_gemm_skred(const float* __restrict__ bias, int M, int N) {
  int i = blockIdx.x * blockDim.x + threadIdx.x;
  int total = M * N;
  if (i >= total) return;
  size_t stride = (size_t)M * N;
  float v = g_score[i] + g_score[i + stride] + g_score[i + 2 * stride] + g_score[i + 3 * stride];
  g_x[i] = v + bias[i % N];
}

// ---------------- dual GEMM for Q and K projections (one dispatch) ----------------
template <int RPB>
__global__ void k_gemmqk(const float* __restrict__ Wq_, const float* __restrict__ Wk_, int M) {
  __shared__ float sA[RPB * 384];
  int half = gridDim.x >> 1;
  bool isK = blockIdx.x >= half;
  int bid = isK ? blockIdx.x - half : blockIdx.x;
  const float* A = isK ? g_k4 : g_q4;
  float* C = isK ? g_k : g_q;
  const float* W = isK ? Wk_ : Wq_;
  const int N = 384;
  int tid = threadIdx.x;
  int r0 = bid * RPB;
  float acc[RPB];
#pragma unroll
  for (int r = 0; r < RPB; ++r) acc[r] = 0.0f;
  for (int idx = tid; idx < RPB * 96; idx += N) {
    int r = idx / 96, q = idx - r * 96;
    ((float4*)sA)[idx] = ((const float4*)(A + (size_t)(r0 + r) * 384))[q];
  }
  __syncthreads();
  const float* Wp = W + tid;
  float w0 = Wp[0], w1 = Wp[N], w2 = Wp[2 * (size_t)N], w3 = Wp[3 * (size_t)N];
#pragma unroll 2
  for (int k = 0; k < 384; k += 4) {
    float n0 = 0.f, n1 = 0.f, n2 = 0.f, n3 = 0.f;
    if (k + 4 < 384) {
      const float* Wn = Wp + (size_t)(k + 4) * N;
      n0 = Wn[0]; n1 = Wn[N]; n2 = Wn[2 * (size_t)N]; n3 = Wn[3 * (size_t)N];
    }
#pragma unroll
    for (int r = 0; r < RPB; ++r) {
      float4 a = *(const float4*)&sA[r * 384 + k];
      acc[r] += a.x * w0 + a.y * w1 + a.z * w2 + a.w * w3;
    }
    w0 = n0; w1 = n1; w2 = n2; w3 = n3;
  }
#pragma unroll
  for (int r = 0; r < RPB; ++r)
    C[(size_t)(r0 + r) * N + tid] = acc[r];
}

// ---------------- fused LayerNorm + GCN weight projection ----------------
__global__ __launch_bounds__(384) void k_lngcn(const float* __restrict__ gg, const float* __restrict__ bb,
                                               const float* __restrict__ Wq, const float* __restrict__ Wk,
                                               const float* __restrict__ Wv, int t) {
  __shared__ float xn[NDIM];
  __shared__ float wred[6];
  int row = blockIdx.x;          // b*t + tt
  int b = row / t, tt = row - b * t;
  int tid = threadIdx.x;
  int wid = tid >> 6, lane = tid & 63;
  float v = g_x[(size_t)row * NDIM + tid];
  float s = v;
#pragma unroll
  for (int off = 32; off > 0; off >>= 1) s += __shfl_xor(s, off);
  if (lane == 0) wred[wid] = s;
  __syncthreads();
  float tot = wred[0] + wred[1] + wred[2] + wred[3] + wred[4] + wred[5];
  float mean = tot * (1.0f / 384.0f);
  __syncthreads();
  float d = v - mean;
  s = d * d;
#pragma unroll
  for (int off = 32; off > 0; off >>= 1) s += __shfl_xor(s, off);
  if (lane == 0) wred[wid] = s;
  __syncthreads();
  tot = wred[0] + wred[1] + wred[2] + wred[3] + wred[4] + wred[5];
  float var = tot * (1.0f / 384.0f);
  float inv = 1.0f / sqrtf(var + 1e-5f);
  xn[tid] = d * inv * gg[tid] + bb[tid];
  __syncthreads();
  int h = tid / DHD, dd = tid - h * DHD;
  const float* xh = &xn[h * DHD];
  float aq = 0.f, ak = 0.f, av = 0.f;
#pragma unroll 4
  for (int e = 0; e < DHD; ++e) {
    float xv_ = xh[e];
    aq += xv_ * Wq[e * DHD + dd];
    ak += xv_ * Wk[e * DHD + dd];
    av += xv_ * Wv[e * DHD + dd];
  }
  size_t o = ((size_t)(b * NHD + h) * t + tt) * DHD + dd;
  g_xq[o] = aq; g_xk[o] = ak; g_xv[o] = av;
}

// ---------------- q4r/k4r = adj @ xq / adj @ xk — 8 rows per block ----------------
__global__ __launch_bounds__(64) void k_adjmm(const int* __restrict__ adji, int use_adj2, int t) {
  __shared__ float arow[8][256];
  int bid = blockIdx.x;
  int nt = t >> 3;
  int lt = bid % nt; int h = (bid / nt) % NHD; int b = bid / (nt * NHD);
  int l0 = lt * 8;
  int tid = threadIdx.x;
  for (int idx = tid; idx < 8 * t; idx += 64) {
    int r = idx / t, s2 = idx - r * t;
    arow[r][s2] = use_adj2 ? g_adj2[((size_t)b * t + l0 + r) * t + s2]
                           : (float)adji[(l0 + r) * 256 + s2];
  }
  __syncthreads();
  if (tid < DHD) {
    const float* xq = g_xq + (size_t)((b * NHD + h) * t) * DHD + tid;
    const float* xk = g_xk + (size_t)((b * NHD + h) * t) * DHD + tid;
    float aq[8] = {0.f, 0.f, 0.f, 0.f, 0.f, 0.f, 0.f, 0.f};
    float ak[8] = {0.f, 0.f, 0.f, 0.f, 0.f, 0.f, 0.f, 0.f};
    for (int s2 = 0; s2 < t; ++s2) {
      float xqv = xq[(size_t)s2 * DHD];
      float xkv = xk[(size_t)s2 * DHD];
#pragma unroll
      for (int r = 0; r < 8; ++r) {
        aq[r] += arow[r][s2] * xqv;
        ak[r] += arow[r][s2] * xkv;
      }
    }
#pragma unroll
    for (int r = 0; r < 8; ++r) {
      size_t o = ((size_t)b * t + l0 + r) * NDIM + h * DHD + tid;
      g_q4[o] = aq[r]; g_k4[o] = ak[r];
    }
  }
}

// ---------------- rm0 = gelu([q,k] @ w_kf)  (b*t, 8) ----------------
__global__ __launch_bounds__(64) void k_kf(const float* __restrict__ Wkf) {
  int row = blockIdx.x;
  int tid = threadIdx.x;
  const float* qrow = g_q + (size_t)row * NDIM;
  const float* krow = g_k + (size_t)row * NDIM;
  float accs[8];
#pragma unroll
  for (int j = 0; j < 8; ++j) accs[j] = 0.f;
  for (int m = tid; m < 768; m += 64) {
    float v = (m < 384) ? qrow[m] : krow[m - 384];
    const float* wr = Wkf + (size_t)m * 8;
#pragma unroll
    for (int j = 0; j < 8; ++j) accs[j] += v * wr[j];
  }
#pragma unroll
  for (int j = 0; j < 8; ++j) {
    float a = accs[j];
    for (int off = 32; off > 0; off >>= 1) a += __shfl_xor(a, off);
    if (tid == 0) g_rm0[(size_t)row * 8 + j] = gelu_f(a);
  }
}

// ---------------- fused rm + rmd ----------------
__global__ __launch_bounds__(256) void k_rmrmd(const float* __restrict__ Wp,
                                               const float* __restrict__ sDp, int t) {
  __shared__ float red[256];
  __shared__ float rm_s[64];
  int b = blockIdx.x; int tid = threadIdx.x;
  int out = tid & 63, slice = tid >> 6;
  int h = out >> 3, g = out & 7;
  int t4 = t >> 2;
  const float* base = g_rm0 + (size_t)b * t * 8 + (size_t)slice * t4 * 8;
  float acc = 0.f;
  for (int tt = 0; tt < t4; ++tt) acc += base[tt * 8 + h] * base[tt * 8 + g];
  red[slice * 64 + out] = acc;
  __syncthreads();
  if (tid < 64)
    rm_s[tid] = red[tid] + red[64 + tid] + red[128 + tid] + red[192 + tid];
  __syncthreads();
  for (int idx = tid; idx < NHD * t; idx += 256) {
    int s = idx % t; int hh = idx / t;
    const float* rm = rm_s + hh * 8;
    float a = 0.f;
#pragma unroll
    for (int gg = 0; gg < 8; ++gg) a += rm[gg] * Wp[gg * t + s];
    float val = a / sDp[hh * t + s];
    g_rmd[((size_t)(b * NHD + hh)) * t + s] = 1.0f / (1.0f + expf(-val));
  }
}

// ---------------- score: 8 q-rows per block; K row in registers ----------------
__global__ void k_score(float scale, int t) {
  __shared__ float qs[8][DHD];
  __shared__ float rl[8];
  int bid = blockIdx.x;
  int nt = t >> 3;
  int lt = bid % nt; int h = (bid / nt) % NHD; int b = bid / (nt * NHD);
  int l0 = lt * 8;
  int tid = threadIdx.x;
  for (int idx = tid; idx < 8 * DHD; idx += t) {
    int r = idx / DHD, d = idx - r * DHD;
    qs[r][d] = g_q[((size_t)b * t + l0 + r) * NDIM + h * DHD + d];
  }
  if (tid < 8) rl[tid] = g_rmd[(size_t)(b * NHD + h) * t + l0 + tid];
  __syncthreads();
  const float* krow = g_k + ((size_t)b * t + tid) * NDIM + h * DHD;
  float4 kr[12];
#pragma unroll
  for (int j = 0; j < 12; ++j) kr[j] = *(const float4*)&krow[j * 4];
  float rmd_s = g_rmd[(size_t)(b * NHD + h) * t + tid];
#pragma unroll
  for (int r = 0; r < 8; ++r) {
    float acc = 0.f;
#pragma unroll
    for (int j = 0; j < 12; ++j) {
      float4 qq = *(const float4*)&qs[r][j * 4];
      acc += kr[j].x * qq.x + kr[j].y * qq.y + kr[j].z * qq.z + kr[j].w * qq.w;
    }
    float v = acc * scale;
    v = (v >= 0.f) ? v : 0.01f * v;
    v = rl[r] * v * rmd_s;
    g_score[((size_t)(b * NHD + h) * t + l0 + r) * t + tid] = v;
  }
}

// ---------------- all-heads mix + mask + softmax per (b,l) ----------------
template <int T>
__global__ void k_mix8(const float* __restrict__ RM, const int* __restrict__ adji,
                       int use_adj2) {
  __shared__ float p[8][T];
  __shared__ float rmat[64];
  int bid = blockIdx.x;
  int l = bid % T, b = bid / T;
  int tt = threadIdx.x;
  if (tt < 64) rmat[tt] = RM[tt];
  __syncthreads();
  float sv[8];
#pragma unroll
  for (int h = 0; h < 8; ++h)
    sv[h] = g_score[((size_t)(b * NHD + h) * T + l) * T + tt];
  bool m = use_adj2 ? (g_adj2[((size_t)b * T + l) * T + tt] > 0.f)
                    : (adji[l * 256 + tt] > 0);
#pragma unroll
  for (int g = 0; g < 8; ++g) {
    float a = 0.f;
#pragma unroll
    for (int h = 0; h < 8; ++h) a += rmat[g * 8 + h] * sv[h];
    p[g][tt] = m ? a : -1e12f;
  }
  __syncthreads();
  int wid = tt >> 6, lane = tt & 63;
  const int NW = T / 64;
  const int RPW = 8 / NW;
  const int EPL = T / 64;
  for (int rr = 0; rr < RPW; ++rr) {
    int row = wid * RPW + rr;
    float mv = -1e30f;
#pragma unroll
    for (int e = 0; e < EPL; ++e) mv = fmaxf(mv, p[row][lane + e * 64]);
#pragma unroll
    for (int off = 32; off > 0; off >>= 1) mv = fmaxf(mv, __shfl_xor(mv, off));
    float sum = 0.f;
#pragma unroll
    for (int e = 0; e < EPL; ++e) {
      float ev = expf(p[row][lane + e * 64] - mv);
      p[row][lane + e * 64] = ev;
      sum += ev;
    }
#pragma unroll
    for (int off = 32; off > 0; off >>= 1) sum += __shfl_xor(sum, off);
    float inv = 1.0f / sum;
#pragma unroll
    for (int e = 0; e < EPL; ++e) p[row][lane + e * 64] *= inv;
  }
  __syncthreads();
#pragma unroll
  for (int h = 0; h < 8; ++h)
    g_score2[((size_t)(b * NHD + h) * T + l) * T + tt] = p[h][tt];
}

// ---------------- v4r = attn @ xv — 8 rows per block ----------------
__global__ __launch_bounds__(64) void k_attnv(int t) {
  __shared__ float arow[8][256];
  int bid = blockIdx.x;
  int nt = t >> 3;
  int lt = bid % nt; int h = (bid / nt) % NHD; int b = bid / (nt * NHD);
  int l0 = lt * 8;
  int tid = threadIdx.x;
  for (int idx = tid; idx < 8 * t; idx += 64) {
    int r = idx / t, s2 = idx - r * t;
    arow[r][s2] = g_score2[((size_t)(b * NHD + h) * t + l0 + r) * t + s2];
  }
  __syncthreads();
  if (tid < DHD) {
    const float* xv = g_xv + (size_t)((b * NHD + h) * t) * DHD + tid;
    float acc[8] = {0.f, 0.f, 0.f, 0.f, 0.f, 0.f, 0.f, 0.f};
    for (int s2 = 0; s2 < t; ++s2) {
      float xvv = xv[(size_t)s2 * DHD];
#pragma unroll
      for (int r = 0; r < 8; ++r) acc[r] += arow[r][s2] * xvv;
    }
#pragma unroll
    for (int r = 0; r < 8; ++r)
      g_q4[((size_t)b * t + l0 + r) * NDIM + h * DHD + tid] = acc[r];
  }
}

// ---------------- gumbel softmax for pooling: tmp[b,j,:] over 256 ----------------
__global__ __launch_bounds__(256) void k_gumbel_pool(uint32_t k0, uint32_t k1) {
  __shared__ double red2[256];
  int bj = blockIdx.x;   // b*64 + j
  int b = bj >> 6, j = bj & 63;
  int tt = threadIdx.x;
  uint32_t n = (uint32_t)bj * 256u + (uint32_t)tt;
  double gum = gumbel_from(k0, k1, n);
  double val = (double)g_logits[((size_t)b * 256 + tt) * 64 + j] + gum;
  red2[tt] = val; __syncthreads();
  for (int s = 128; s > 0; s >>= 1) { if (tt < s) red2[tt] = fmax(red2[tt], red2[tt + s]); __syncthreads(); }
  double mx = red2[0]; __syncthreads();
  double e = exp(val - mx);
  red2[tt] = e; __syncthreads();
  for (int s = 128; s > 0; s >>= 1) { if (tt < s) red2[tt] += red2[tt + s]; __syncthreads(); }
  g_tmp[(size_t)bj * 256 + tt] = (float)(e / red2[0]);
}

// ---------------- xb[b,j,:] = tmp[b,j,:] @ x[b,:,:] ----------------
__global__ __launch_bounds__(384) void k_poolx() {
  __shared__ float trow[256];
  int bj = blockIdx.x; int b = bj >> 6;
  int tid = threadIdx.x;
  if (tid < 256) trow[tid] = g_tmp[(size_t)bj * 256 + tid];
  __syncthreads();
  float acc = 0.f;
  const float* xb = g_x + (size_t)b * 256 * NDIM + tid;
  for (int tt = 0; tt < 256; ++tt) acc += trow[tt] * xb[(size_t)tt * NDIM];
  g_xb[(size_t)bj * NDIM + tid] = acc;
}

__global__ void k_copyx(int n) {
  int i = blockIdx.x * blockDim.x + threadIdx.x;
  if (i < n) g_x[i] = g_xb[i];
}

// ---------------- e1[b,l,t] = sum_s tmp[b,l,s]*adj[s,t] ----------------
__global__ __launch_bounds__(256) void k_pooladj1(const int* __restrict__ adji) {
  __shared__ float trow[256];
  int bl = blockIdx.x;
  int tid = threadIdx.x;
  trow[tid] = g_tmp[(size_t)bl * 256 + tid];
  __syncthreads();
  float acc = 0.f;
  for (int s = 0; s < 256; ++s) acc += trow[s] * (float)adji[s * 256 + tid];
  g_e1[(size_t)bl * 256 + tid] = acc;
}

// ---------------- adj2[b,l,m] = sum_t e1[b,l,t]*tmp[b,m,t] ----------------
__global__ __launch_bounds__(64) void k_pooladj2() {
  __shared__ float erow[256];
  int bl = blockIdx.x; int b = bl >> 6;
  int tid = threadIdx.x;
  for (int s = tid; s < 256; s += 64) erow[s] = g_e1[(size_t)bl * 256 + s];
  __syncthreads();
  const float* tm = g_tmp + ((size_t)b * 64 + tid) * 256;
  float acc = 0.f;
  for (int s = 0; s < 256; ++s) acc += erow[s] * tm[s];
  g_adj2[(size_t)bl * 64 + tid] = acc;
}

// ---------------- final logits: x @ upoolout_w + b ----------------
__global__ __launch_bounds__(64) void k_outlogits(const float* __restrict__ w, const float* __restrict__ bias) {
  int row = blockIdx.x;
  int tid = threadIdx.x;
  const float* x = g_x + (size_t)row * NDIM;
  float acc = 0.f;
  for (int c = tid; c < NDIM; c += 64) acc += x[c] * w[c];
  for (int off = 32; off > 0; off >>= 1) acc += __shfl_xor(acc, off);
  if (tid == 0) g_lg2[row] = acc + bias[0];
}

// ---------------- final gumbel softmax + weighted sum -> out ----------------
__global__ __launch_bounds__(384) void k_final(uint32_t k0, uint32_t k1, float* __restrict__ out) {
  __shared__ double sv[64];
  __shared__ double sp[64];
  int b = blockIdx.x;
  int tid = threadIdx.x;
  if (tid < 64) {
    uint32_t n = (uint32_t)(b * 64 + tid);
    sv[tid] = (double)g_lg2[b * 64 + tid] + gumbel_from(k0, k1, n);
  }
  __syncthreads();
  double mx = -1e30;
  for (int i2 = 0; i2 < 64; ++i2) mx = fmax(mx, sv[i2]);
  if (tid < 64) sp[tid] = exp(sv[tid] - mx);
  __syncthreads();
  double sum = 0.;
  for (int i2 = 0; i2 < 64; ++i2) sum += sp[i2];
  float acc = 0.f;
  const float* xb = g_x + (size_t)b * 64 * NDIM + tid;
  for (int tt = 0; tt < 64; ++tt) acc += (float)(sp[tt] / sum) * xb[(size_t)tt * NDIM];
  out[(size_t)b * NDIM + tid] = acc;
}

// ---------------- host ----------------
extern "C" void kernel_launch(void* const* d_in, const int* in_sizes, int n_in,
                              void* d_out, int out_size, void* d_ws, size_t ws_size,
                              hipStream_t stream) {
  const float* img = (const float*)d_in[0];
  const int* adj = (const int*)d_in[1];
  const float* ln_g = (const float*)d_in[2];
  const float* ln_b = (const float*)d_in[3];
  const float* gcn_wq = (const float*)d_in[4];
  const float* gcn_wk = (const float*)d_in[5];
  const float* gcn_wv = (const float*)d_in[6];
  const float* wq = (const float*)d_in[7];
  const float* wk = (const float*)d_in[8];
  const float* wv = (const float*)d_in[9];
  const float* w_kf = (const float*)d_in[10];
  const float* w_kf2 = (const float*)d_in[11];
  const float* w_kf3 = (const float*)d_in[12];
  const float* sD = (const float*)d_in[13];
  const float* sD2 = (const float*)d_in[14];
  const float* randmat = (const float*)d_in[15];
  const float* conv1_w = (const float*)d_in[16];
  const float* conv1_b = (const float*)d_in[17];
  const float* bn_g = (const float*)d_in[18];
  const float* bn_b = (const float*)d_in[19];
  const float* conv2_w = (const float*)d_in[20];
  const float* conv2_b = (const float*)d_in[21];
  const float* emb_w = (const float*)d_in[22];
  const float* emb_b = (const float*)d_in[23];
  const float* upool_w = (const float*)d_in[24];
  const float* upool_b = (const float*)d_in[25];
  const float* upoolout_w = (const float*)d_in[26];
  const float* upoolout_b = (const float*)d_in[27];
  float* out = (float*)d_out;

  uint32_t k2a, k2b, k99a, k99b;
  threefry2x32(0u, 42u, 0u, 2u, &k2a, &k2b);
  threefry2x32(0u, 42u, 0u, 99u, &k99a, &k99b);

  const float SCALE = (float)(1.0 / sqrt(384.0));

  k_patch<<<2048 * 4, 256, 0, stream>>>(img, conv1_w, conv1_b, bn_g, bn_b, conv2_w, conv2_b);
  k_gemm_sk<<<1024, 384, 0, stream>>>(emb_w, 2048, 1536, 384);
  k_gemm_skred<<<(2048 * 384 + 255) / 256, 256, 0, stream>>>(emb_b, 2048, 384);

  auto attention = [&](int i, int t, int label) {
    int rows = NB * t;
    int bht8 = NB * NHD * t / 8;
    int use_adj2 = (t == 64) ? 1 : 0;
    k_lngcn<<<rows, 384, 0, stream>>>(ln_g + i * 384, ln_b + i * 384,
                                      gcn_wq + i * 2304, gcn_wk + i * 2304,
                                      gcn_wv + i * 2304, t);
    k_adjmm<<<bht8, 64, 0, stream>>>(adj, use_adj2, t);
    if (rows == 2048) {
      k_gemmqk<4><<<1024, 384, 0, stream>>>(wq + i * 147456, wk + i * 147456, rows);
    } else {
      k_gemmqk<2><<<512, 384, 0, stream>>>(wq + i * 147456, wk + i * 147456, rows);
    }
    k_kf<<<rows, 64, 0, stream>>>(w_kf + i * 6144);
    const float* Wp = label ? (w_kf3 + i * 512) : (w_kf2 + i * 2048);
    const float* sDp = label ? (sD2 + i * 512) : (sD + i * 2048);
    k_rmrmd<<<NB, 256, 0, stream>>>(Wp, sDp, t);
    k_score<<<bht8, t, 0, stream>>>(SCALE, t);
    if (t == 256) {
      k_mix8<256><<<rows, 256, 0, stream>>>(randmat + i * 64, adj, use_adj2);
    } else {
      k_mix8<64><<<rows, 64, 0, stream>>>(randmat + i * 64, adj, use_adj2);
    }
    k_attnv<<<bht8, 64, 0, stream>>>(t);
    if (rows == 2048) {
      k_gemm<4><<<512, 384, 4 * 384 * sizeof(float), stream>>>(
          wv + i * 147456, nullptr, SEL_Q4, SEL_X, SEL_X, rows, 384, 384, 1);
    } else {
      k_gemm<2><<<256, 384, 2 * 384 * sizeof(float), stream>>>(
          wv + i * 147456, nullptr, SEL_Q4, SEL_X, SEL_X, rows, 384, 384, 1);
    }
  };

  attention(0, 256, 0);
  attention(1, 256, 0);

  // pooling at i==2
  k_gemm<2><<<1024, 64, 2 * 384 * sizeof(float), stream>>>(
      upool_w, upool_b, SEL_X, SEL_LOGITS, -1, 2048, 384, 64, 0);
  k_gumbel_pool<<<512, 256, 0, stream>>>(k2a, k2b);
  k_poolx<<<512, 384, 0, stream>>>();
  k_copyx<<<(NB * 64 * NDIM + 255) / 256, 256, 0, stream>>>(NB * 64 * NDIM);
  k_pooladj1<<<512, 256, 0, stream>>>(adj);
  k_pooladj2<<<512, 64, 0, stream>>>();

  attention(2, 64, 1);
  attention(3, 64, 1);

  k_outlogits<<<512, 64, 0, stream>>>(upoolout_w, upoolout_b);
  k_final<<<8, 384, 0, stream>>>(k99a, k99b, out);
}